// Round 1
// baseline (66.235 us; speedup 1.0000x reference)
//
#include <hip/hip_runtime.h>

// MultiLabelAdaptiveMarginLoss: B=256, C=4096, K=32
// loss = (1/C) * sum_{b,k valid} sum_{j != t} relu(1 + (m_t - m_j) - (x_t - x_j))
// Rewrite: diff = a_k + c_j, a_k = 1 + m_t - x_t, c_j = x_j - m_j.
// j==t term is relu(1)=1 -> sum over all j, subtract 1 per valid target.

#define BB 256
#define CC 4096
#define KK 32
#define THREADS 256

__global__ __launch_bounds__(THREADS) void mlam_rows(
    const float* __restrict__ input,
    const float* __restrict__ margin,
    const int* __restrict__ target,
    float* __restrict__ partials) {

    __shared__ float sc[CC];     // c_j = input_j - margin_j for this row
    __shared__ float sa[KK];     // a_k = 1 + m_t - x_t (-1e30 for padded)
    __shared__ int   svalid;
    __shared__ float swave[THREADS / 64];

    const int b   = blockIdx.x;
    const int tid = threadIdx.x;
    const float* in_row = input  + (size_t)b * CC;
    const float* mg_row = margin + (size_t)b * CC;

    // Stage c_j into LDS, float4-vectorized, coalesced.
    const float4* in4 = (const float4*)in_row;
    const float4* mg4 = (const float4*)mg_row;
    float4* sc4 = (float4*)sc;
#pragma unroll
    for (int i = 0; i < CC / 4 / THREADS; ++i) {       // 4 iters
        int idx = tid + i * THREADS;
        float4 x = in4[idx];
        float4 m = mg4[idx];
        sc4[idx] = make_float4(x.x - m.x, x.y - m.y, x.z - m.z, x.w - m.w);
    }
    if (tid == 0) svalid = 0;
    __syncthreads();

    // Lanes 0..31 gather per-target scalars.
    if (tid < KK) {
        int t = target[b * KK + tid];
        if (t >= 0) {
            sa[tid] = 1.0f + mg_row[t] - in_row[t];
            atomicAdd(&svalid, 1);
        } else {
            sa[tid] = -1e30f;   // relu(a+c) == 0 for all j
        }
    }
    __syncthreads();

    // Broadcast a_k into registers.
    float a[KK];
#pragma unroll
    for (int k = 0; k < KK; ++k) a[k] = sa[k];

    // Each thread: 4 float4 LDS reads x 32 targets = 512 relu terms.
    float acc = 0.0f;
#pragma unroll
    for (int i = 0; i < CC / 4 / THREADS; ++i) {
        float4 c = sc4[tid + i * THREADS];
#pragma unroll
        for (int k = 0; k < KK; ++k) {
            acc += fmaxf(a[k] + c.x, 0.0f);
            acc += fmaxf(a[k] + c.y, 0.0f);
            acc += fmaxf(a[k] + c.z, 0.0f);
            acc += fmaxf(a[k] + c.w, 0.0f);
        }
    }

    // Wave reduce (wave64), then cross-wave via LDS.
#pragma unroll
    for (int off = 32; off > 0; off >>= 1)
        acc += __shfl_down(acc, off, 64);
    if ((tid & 63) == 0) swave[tid >> 6] = acc;
    __syncthreads();
    if (tid == 0) {
        float tot = 0.0f;
#pragma unroll
        for (int w = 0; w < THREADS / 64; ++w) tot += swave[w];
        partials[b] = tot - (float)svalid;   // remove j==t terms
    }
}

__global__ __launch_bounds__(THREADS) void mlam_reduce(
    const float* __restrict__ partials,
    float* __restrict__ out) {
    __shared__ float swave[THREADS / 64];
    const int tid = threadIdx.x;
    float v = partials[tid];   // exactly BB == THREADS partials
#pragma unroll
    for (int off = 32; off > 0; off >>= 1)
        v += __shfl_down(v, off, 64);
    if ((tid & 63) == 0) swave[tid >> 6] = v;
    __syncthreads();
    if (tid == 0) {
        float tot = 0.0f;
#pragma unroll
        for (int w = 0; w < THREADS / 64; ++w) tot += swave[w];
        out[0] = tot * (1.0f / (float)CC);
    }
}

extern "C" void kernel_launch(void* const* d_in, const int* in_sizes, int n_in,
                              void* d_out, int out_size, void* d_ws, size_t ws_size,
                              hipStream_t stream) {
    const float* input  = (const float*)d_in[0];   // [B, C] fp32
    const float* margin = (const float*)d_in[1];   // [B, C] fp32
    const int*   target = (const int*)d_in[2];     // [B, K] int
    float* out      = (float*)d_out;               // scalar
    float* partials = (float*)d_ws;                // >= B floats

    mlam_rows<<<BB, THREADS, 0, stream>>>(input, margin, target, partials);
    mlam_reduce<<<1, THREADS, 0, stream>>>(partials, out);
}